// Round 5
// baseline (145.812 us; speedup 1.0000x reference)
//
#include <hip/hip_runtime.h>

// ConvByMoveLayer: out[b,f,o] = sum_m sum_c x[b, mask[m,f], c] * W[m,c,o] + bias[f,o]
// B=128, F=4096, C=32, O=32, M=9.
//
// Round 10: two-pass fp16 with MFMA-native permuted layout; no LDS staging.
//   r7/r8/r9 all pinned at ~65us ~ gather-bytes / 9 TB/s => gathers were
//   served by Infinity Cache, not XCD L2 (2MB slice + next phase + stores
//   oversubscribed the 4MB L2). r9's GLL path also failed correctness
//   (suspect: vmcnt-retire vs LDS-write visibility without a barrier), so
//   the gather returns to plain per-lane loads (proven in r5-r8).
//   Fixes here:
//   - fp16 staging halves gather bytes; 4-batch slices = 1MB/XCD/phase.
//   - Permuted row layout xh[f][b_hi][k][h][b_lo][j] (k=c>>4, h=(c>>3)&1,
//     j=c&7, b=b_hi*4+b_lo): one halfx8 load per (move, K-slice) IS the MFMA
//     A-fragment, and its 8 lanes per field cover ONE FULL 128B line
//     => 8 fully-consumed lines/instr, 288 line-requests/wave (GLL-grade
//     efficiency, zero LDS/transpose/swizzle/barriers in the gather).
//     B-side sw mapping unchanged (slice t covers c in [16(t&1),16(t&1)+16)).
//   - pass1 blocks write each (phase,xcd) slice from that XCD (blk&7=xcd,
//     ascending phase); pass2 walks phases in REVERSE to hit warm slices.
//   Numerics identical to r5 (same RNE fp16 cast, same MFMA order).

#define B_ 128
#define F_ 4096
#define C_ 32
#define O_ 32
#define M_ 9
#define T_ 18          // K=16 MFMA slices (M_*C_/16)

typedef _Float16 halfx4 __attribute__((ext_vector_type(4)));
typedef _Float16 halfx8 __attribute__((ext_vector_type(8)));
typedef float floatx4 __attribute__((ext_vector_type(4)));
typedef float floatx16 __attribute__((ext_vector_type(16)));

// ---------------- Pass 1: fp32 x[b][f][c] -> fp16 xh (permuted) ----------------
// pos_halves(f,b,c) = f*4096 + (b>>2)*128 + ((c>>4)*8 + ((c>>3)&1)*4 + (b&3))*8 + (c&7)
// grid 4096: blk&7 = xcd, (blk>>3)&127 = field tile, blk>>10 = phase (ascending).
__global__ __launch_bounds__(256) void pass1_cvt(
    const float* __restrict__ x, _Float16* __restrict__ xh)
{
    const int blk = blockIdx.x;
    const int xcd = blk & 7;
    const int ft  = (blk >> 3) & 127;
    const int p   = blk >> 10;
    const int b0  = (p * 8 + xcd) * 4;   // this (phase,xcd) 4-batch slice
    const int f0  = ft * 32;
    const int fl  = threadIdx.x >> 3;    // field 0..31
    const int c4  = (threadIdx.x & 7) * 4;
    const int k   = c4 >> 4;
    const int h   = (c4 >> 3) & 1;
    const int j0  = c4 & 7;
    _Float16* dst = xh + (size_t)(f0 + fl) * (B_ * C_) + (b0 >> 2) * 128
                    + (k * 8 + h * 4) * 8 + j0;
#pragma unroll
    for (int q = 0; q < 4; ++q) {        // q = b_lo
        const floatx4 v = __builtin_nontemporal_load(
            reinterpret_cast<const floatx4*>(
                x + ((size_t)(b0 + q) * F_ + f0 + fl) * C_ + c4));
        halfx4 hv;
#pragma unroll
        for (int jj = 0; jj < 4; ++jj) hv[jj] = (_Float16)v[jj];
        *reinterpret_cast<halfx4*>(dst + q * 8) = hv;
    }
}

// ---------------- Pass 2: direct-fragment gather + MFMA ----------------
// grid 4096: blk&7 = xcd, (blk>>3)&127 = field tile, phase = 3-(blk>>10).
__global__ __launch_bounds__(256, 3) void pass2_gemm(
    const _Float16* __restrict__ xh, const int* __restrict__ mask,
    const float* __restrict__ coeffs, const float* __restrict__ biases,
    float* __restrict__ out)
{
    __shared__ _Float16 sw[T_ * 64 * 8];   // 18 KB B-fragments (shared by 4 waves)
    const int tid = threadIdx.x;

    // sw[t][lane][j] = W[m=t>>1][c = 16*(t&1) + 8*(lane>>5) + j][o = lane&31]
    for (int id = tid; id < T_ * 64; id += 256) {
        const int t  = id >> 6;
        const int L  = id & 63;
        const int m  = t >> 1;
        const int cb = 16 * (t & 1) + 8 * (L >> 5);
        const int oo = L & 31;
        halfx8 w;
#pragma unroll
        for (int jj = 0; jj < 8; ++jj)
            w[jj] = (_Float16)coeffs[(m * C_ + cb + jj) * O_ + oo];
        *reinterpret_cast<halfx8*>(&sw[id * 8]) = w;
    }
    __syncthreads();

    const int blk = blockIdx.x;
    const int xcd = blk & 7;
    const int ft  = (blk >> 3) & 127;
    const int p   = 3 - (blk >> 10);     // REVERSED: warmest slices first
    const int b0  = (p * 8 + xcd) * 4;
    const int f0  = ft * 32;

    const int wave = tid >> 6;
    const int lane = tid & 63;
    const int h    = lane >> 5;          // K-half selector
    const int row  = lane & 31;          // MFMA M-row = fi*4 + bp
    const int fi   = row >> 2;           // field within wave tile (0..7)
    const int bp   = row & 3;            // batch within slice (0..3)
    const int o    = lane & 31;          // C/D col = output channel
    const int fw   = f0 + wave * 8;
    const int f    = fw + fi;            // per-lane A-row field

    int sidx[M_];
#pragma unroll
    for (int m = 0; m < M_; ++m) sidx[m] = mask[m * F_ + f];

    // Lane's fragment position within any field row (halves):
    //   frag(k) at (b0>>2)*128 + (k*8 + h*4 + bp)*8  -- one halfx8 = full frag.
    const _Float16* xb = xh + (b0 >> 2) * 128 + (h * 4 + bp) * 8;

    // 36 independent 16B gathers; per instr: 8 fields x one FULL 128B line.
    halfx8 a[T_];
#pragma unroll
    for (int m = 0; m < M_; ++m) {
        const _Float16* rp = xb + (size_t)sidx[m] * (B_ * C_);
        a[2 * m]     = *reinterpret_cast<const halfx8*>(rp);        // k=0
        a[2 * m + 1] = *reinterpret_cast<const halfx8*>(rp + 64);   // k=1 (+8 chunks)
    }

    floatx16 acc;
#pragma unroll
    for (int i = 0; i < 16; ++i) acc[i] = 0.0f;
#pragma unroll
    for (int t = 0; t < T_; ++t) {
        const halfx8 bwt = *reinterpret_cast<const halfx8*>(&sw[(t * 64 + lane) * 8]);
        acc = __builtin_amdgcn_mfma_f32_32x32x16_f16(a[t], bwt, acc, 0, 0, 0);
    }

    // C/D layout (m74/m101): col = lane&31, orow = (r&3) + 8*(r>>2) + 4*h
    //   => output field offset = 2*(r>>2) + h, batch = r&3.
    float bv[4];
#pragma unroll
    for (int q = 0; q < 4; ++q)
        bv[q] = biases[(size_t)(fw + 2 * q + h) * O_ + o];

#pragma unroll
    for (int r = 0; r < 16; ++r) {
        const int q   = r >> 2;          // compile-time
        const int obp = r & 3;           // compile-time
        const float v = acc[r] + bv[q];
        __builtin_nontemporal_store(
            v, &out[((size_t)(b0 + obp) * F_ + fw + 2 * q + h) * O_ + o]);
    }
}

// ---------------- Fallback (correct, slow) if ws too small ----------------
__global__ __launch_bounds__(256) void fallback_kernel(
    const float* __restrict__ x, const int* __restrict__ mask,
    const float* __restrict__ coeffs, const float* __restrict__ biases,
    float* __restrict__ out)
{
    int gid = blockIdx.x * 256 + threadIdx.x;   // over B*F*O
    int o = gid & (O_ - 1);
    int f = (gid >> 5) & (F_ - 1);
    int b = gid >> 17;
    float acc = biases[f * O_ + o];
    for (int m = 0; m < M_; ++m) {
        int s = mask[m * F_ + f];
        const float* xr = x + ((size_t)b * F_ + s) * C_;
        const float* wr = coeffs + (m * C_) * O_ + o;
#pragma unroll
        for (int c = 0; c < C_; ++c)
            acc += xr[c] * wr[c * O_];
    }
    out[gid] = acc;
}

extern "C" void kernel_launch(void* const* d_in, const int* in_sizes, int n_in,
                              void* d_out, int out_size, void* d_ws, size_t ws_size,
                              hipStream_t stream) {
    const float* x      = (const float*)d_in[0];
    const int*   mask   = (const int*)d_in[1];
    const float* coeffs = (const float*)d_in[2];
    const float* biases = (const float*)d_in[3];
    float* out = (float*)d_out;

    const size_t need = (size_t)F_ * B_ * C_ * sizeof(_Float16);   // 32 MB
    if (ws_size >= need) {
        _Float16* xh = (_Float16*)d_ws;
        pass1_cvt<<<4 * 8 * 128, 256, 0, stream>>>(x, xh);
        pass2_gemm<<<4 * 8 * 128, 256, 0, stream>>>(xh, mask, coeffs, biases, out);
    } else {
        fallback_kernel<<<(B_ * F_ * O_) / 256, 256, 0, stream>>>(x, mask, coeffs, biases, out);
    }
}